// Round 4
// baseline (758.012 us; speedup 1.0000x reference)
//
#include <hip/hip_runtime.h>

typedef _Float16 f16;
typedef __attribute__((ext_vector_type(8))) _Float16 f16x8;
typedef __attribute__((ext_vector_type(4))) float f32x4;

#define HD 512
#define NBSEQ 256
#define LSEQ 256
#define PREDN 96
#define SLOT 262144   // f16 elements per 512x512 matrix

// ws layout (f16), total 39 SLOTs = 19.5 MB:
//   slot 0      : TX (Wxh swizzled)
//   slot 1..16  : T1..T16      (T-form of A^k, A = Whh^T)
//   slot 17..20 : T32, T48, T64, T80
//   slot 21..27 : R1,R2,R4,R8,R16,R32,R64 (row-major f16)
//   slot 28..35 : Hb [16][256][512] f16
//   slot 36..38 : Pb [5][256][512] f16  (Pb_c = H15 @ A^{16c}, c=1..5)
// T-form: T(kk,nt,lane,j) = M[k][n], k=kk*32+(lane>>4)*8+j, n=nt*16+(lane&15)

// ---------------------------------------------------------------------------
__global__ __launch_bounds__(512, 1) void prep(const float* __restrict__ Wxh,
                                               const float* __restrict__ Whh,
                                               f16* __restrict__ ws) {
    int gid = blockIdx.x * 512 + threadIdx.x;     // grid 192 -> gid < 98304
    if (gid < 65536) {
        int table = gid >> 15;
        int rem = gid & 32767;
        int kk = rem >> 11;
        int nt = (rem >> 6) & 31;
        int l = rem & 63;
        int n = nt * 16 + (l & 15);
        int k = kk * 32 + (l >> 4) * 8;
        const float* W = (table ? Whh : Wxh) + (size_t)n * HD + k;
        f16x8 v;
#pragma unroll
        for (int j = 0; j < 8; j++) v[j] = (f16)W[j];
        *reinterpret_cast<f16x8*>(ws + (size_t)gid * 8) = v;
    } else {
        int idx = gid - 65536;                    // 0..32767
        int m = idx >> 6, kc = (idx & 63) * 8;
        f16* R1 = ws + (size_t)SLOT * 21;
        f16x8 v;
#pragma unroll
        for (int j = 0; j < 8; j++) v[j] = (f16)Whh[(size_t)(kc + j) * HD + m];
        *reinterpret_cast<f16x8*>(R1 + (size_t)m * HD + kc) = v;
    }
}

// ---------------------------------------------------------------------------
// gemm_xw: xW = x @ Wxh^T -> fp32 in-place into rec. (structure verified R1-R3)
// ---------------------------------------------------------------------------
__global__ __launch_bounds__(512, 1) void gemm_xw(const float* __restrict__ x,
                                                  const f16* __restrict__ bsw,
                                                  float* __restrict__ xw) {
    __shared__ f16 Al[2][128][40];
    __shared__ f16 Bl[2][16384];
    const int tid = threadIdx.x;
    const int w = tid >> 6, l = tid & 63;
    const size_t r0 = (size_t)blockIdx.x * 128;

    f32x4 acc[8][4];
#pragma unroll
    for (int mt = 0; mt < 8; mt++)
#pragma unroll
        for (int nt = 0; nt < 4; nt++) acc[mt][nt] = (f32x4)0.f;

    const int arow_l = l & 15;
    const int akc = (l >> 4) * 8;
    const int srow = tid >> 2, sc8 = (tid & 3) * 8;

    for (int kk = 0; kk < 16; kk++) {
        const int buf = kk & 1;
        {
            const float* src = x + (r0 + srow) * HD + kk * 32 + sc8;
            float4 f0 = *reinterpret_cast<const float4*>(src);
            float4 f1 = *reinterpret_cast<const float4*>(src + 4);
            f16x8 a;
            a[0] = (f16)f0.x; a[1] = (f16)f0.y; a[2] = (f16)f0.z; a[3] = (f16)f0.w;
            a[4] = (f16)f1.x; a[5] = (f16)f1.y; a[6] = (f16)f1.z; a[7] = (f16)f1.w;
            *reinterpret_cast<f16x8*>(&Al[buf][srow][sc8]) = a;
        }
        {
            const f16* bsrc = bsw + (size_t)kk * 16384 + tid * 8;
#pragma unroll
            for (int i = 0; i < 4; i++)
                *reinterpret_cast<f16x8*>(&Bl[buf][i * 4096 + tid * 8]) =
                    *reinterpret_cast<const f16x8*>(bsrc + i * 4096);
        }
        __syncthreads();

        f16x8 af[8];
#pragma unroll
        for (int mt = 0; mt < 8; mt++)
            af[mt] = *reinterpret_cast<const f16x8*>(&Al[buf][mt * 16 + arow_l][akc]);
#pragma unroll
        for (int nt = 0; nt < 4; nt++) {
            f16x8 bf = *reinterpret_cast<const f16x8*>(&Bl[buf][((w * 4 + nt) * 64 + l) * 8]);
#pragma unroll
            for (int mt = 0; mt < 8; mt++)
                acc[mt][nt] = __builtin_amdgcn_mfma_f32_16x16x32_f16(af[mt], bf, acc[mt][nt], 0, 0, 0);
        }
    }
#pragma unroll
    for (int mt = 0; mt < 8; mt++)
#pragma unroll
        for (int nt = 0; nt < 4; nt++)
#pragma unroll
            for (int r = 0; r < 4; r++) {
                size_t row = r0 + mt * 16 + (l >> 4) * 4 + r;
                int col = w * 64 + nt * 16 + arow_l;
                xw[row * HD + col] = acc[mt][nt][r];
            }
}

// ---------------------------------------------------------------------------
// core128: C[128,512] = A[128,512](f16 row-major) @ Y(T-form), K=512.
// ---------------------------------------------------------------------------
__device__ __forceinline__ void core128(const f16* __restrict__ Asrc,
                                        const f16* __restrict__ Y,
                                        f16 (*Al)[128][40],
                                        f32x4 (*acc)[4], int tid) {
    const int w = tid >> 6, l = tid & 63;
    const int srow = tid >> 2, sc8 = (tid & 3) * 8;
    const int arow = l & 15, ak = (l >> 4) * 8;
    for (int kk = 0; kk < 16; kk++) {
        const int buf = kk & 1;
        *reinterpret_cast<f16x8*>(&Al[buf][srow][sc8]) =
            *reinterpret_cast<const f16x8*>(Asrc + (size_t)srow * HD + kk * 32 + sc8);
        __syncthreads();
        f16x8 af[8];
#pragma unroll
        for (int mt = 0; mt < 8; mt++)
            af[mt] = *reinterpret_cast<const f16x8*>(&Al[buf][mt * 16 + arow][ak]);
#pragma unroll
        for (int nt = 0; nt < 4; nt++) {
            f16x8 b = *reinterpret_cast<const f16x8*>(Y + (size_t)(kk * 32 + w * 4 + nt) * 512 + l * 8);
#pragma unroll
            for (int mt = 0; mt < 8; mt++)
                acc[mt][nt] = __builtin_amdgcn_mfma_f32_16x16x32_f16(af[mt], b, acc[mt][nt], 0, 0, 0);
        }
    }
}

// T-form scatter index for value M[m][n]
__device__ __forceinline__ size_t tform_ix(int m, int n) {
    return (((size_t)(m >> 5) * 32 + (n >> 4)) * 64 +
            (((m >> 3) & 3) * 16 + (n & 15))) * 8 + (m & 7);
}

// ---------------------------------------------------------------------------
// powlevel: doubling levels 1-4 (verified R2/R3). out T[h+1+j0] = R @ T[1+j0].
// ---------------------------------------------------------------------------
__global__ __launch_bounds__(512, 1) void powlevel(const f16* __restrict__ RX,
                                                   f16* __restrict__ ws,
                                                   f16* __restrict__ Rsq,
                                                   int h) {
    __shared__ f16 Al[2][128][40];
    const int tid = threadIdx.x;
    const int j0 = blockIdx.x >> 2, mtile = blockIdx.x & 3;
    const int m0 = mtile * 128;
    const f16* Y = ws + (size_t)SLOT * (1 + j0);
    f16* Tout = ws + (size_t)SLOT * (h + 1 + j0);

    f32x4 acc[8][4];
#pragma unroll
    for (int mt = 0; mt < 8; mt++)
#pragma unroll
        for (int nt = 0; nt < 4; nt++) acc[mt][nt] = (f32x4)0.f;

    core128(RX + (size_t)m0 * HD, Y, Al, acc, tid);

    const int w = tid >> 6, l = tid & 63;
    const bool doR = (1 + j0) == h;
#pragma unroll
    for (int mt = 0; mt < 8; mt++)
#pragma unroll
        for (int nt = 0; nt < 4; nt++)
#pragma unroll
            for (int r = 0; r < 4; r++) {
                int m = m0 + mt * 16 + (l >> 4) * 4 + r;
                int n = w * 64 + nt * 16 + (l & 15);
                f16 v = (f16)acc[mt][nt][r];
                Tout[tform_ix(m, n)] = v;
                if (doR) Rsq[(size_t)m * HD + n] = v;
            }
}

// ---------------------------------------------------------------------------
// powB: boundary powers. pair = bx>>2 selects (Ya->Ta) or (Yb->Tb);
// R-form written for pair==rpair.
// ---------------------------------------------------------------------------
__global__ __launch_bounds__(512, 1) void powB(const f16* __restrict__ R,
                                               const f16* __restrict__ Ya, f16* __restrict__ Ta,
                                               const f16* __restrict__ Yb, f16* __restrict__ Tb,
                                               f16* __restrict__ Rout, int rpair) {
    __shared__ f16 Al[2][128][40];
    const int tid = threadIdx.x;
    const int pair = blockIdx.x >> 2, mtile = blockIdx.x & 3;
    const int m0 = mtile * 128;
    const f16* Y = pair ? Yb : Ya;
    f16* Tout = pair ? Tb : Ta;

    f32x4 acc[8][4];
#pragma unroll
    for (int mt = 0; mt < 8; mt++)
#pragma unroll
        for (int nt = 0; nt < 4; nt++) acc[mt][nt] = (f32x4)0.f;

    core128(R + (size_t)m0 * HD, Y, Al, acc, tid);

    const int w = tid >> 6, l = tid & 63;
    const bool doR = (Rout != nullptr) && (pair == rpair);
#pragma unroll
    for (int mt = 0; mt < 8; mt++)
#pragma unroll
        for (int nt = 0; nt < 4; nt++)
#pragma unroll
            for (int r = 0; r < 4; r++) {
                int m = m0 + mt * 16 + (l >> 4) * 4 + r;
                int n = w * 64 + nt * 16 + (l & 15);
                f16 v = (f16)acc[mt][nt][r];
                Tout[tform_ix(m, n)] = v;
                if (doR) Rout[(size_t)m * HD + n] = v;
            }
}

// ---------------------------------------------------------------------------
// phaseA v4: breg truly resident (256-VGPR cap), xW(t+1) prefetched,
// streamed-B pipeline wraps across steps. 256 WGs, M=16.
// ---------------------------------------------------------------------------
__global__ __launch_bounds__(512, 1) void phaseA(float* __restrict__ rec,
                                                 const f16* __restrict__ T1) {
    __shared__ f16 hb[2][16][520];
    const int tid = threadIdx.x, w = tid >> 6, l = tid & 63;
    const int c = blockIdx.x >> 4, sg = blockIdx.x & 15;
    const int s0 = sg * 16;
    {
        f16* hp = &hb[0][0][0];
        for (int i = tid; i < 16 * 520; i += 512) hp[i] = (f16)0.f;
    }
    const int arow = l & 15, ak = (l >> 4) * 8;
    const f16* bbase = T1 + (size_t)l * 8;

    // resident half: kk = 8..15 (128 VGPR; requires the 256-VGPR budget)
    f16x8 breg[8][4];
#pragma unroll
    for (int kk = 0; kk < 8; kk++)
#pragma unroll
        for (int nt = 0; nt < 4; nt++)
            breg[kk][nt] = *reinterpret_cast<const f16x8*>(
                bbase + (size_t)((kk + 8) * 32 + w * 4 + nt) * 512);

    // streamed-half pipeline registers; invariant: at step entry sb[q] = kk q
    f16x8 sb[2][4];
#pragma unroll
    for (int q = 0; q < 2; q++)
#pragma unroll
        for (int nt = 0; nt < 4; nt++)
            sb[q][nt] = *reinterpret_cast<const f16x8*>(
                bbase + (size_t)(q * 32 + w * 4 + nt) * 512);

    // xW prefetch for t0
    float xwv[4][4], xwn[4][4];
#pragma unroll
    for (int nt = 0; nt < 4; nt++)
#pragma unroll
        for (int r = 0; r < 4; r++) {
            int s = s0 + (l >> 4) * 4 + r;
            xwv[nt][r] = rec[((size_t)s * LSEQ + c * 16) * HD + w * 64 + nt * 16 + arow];
        }
    __syncthreads();

    int cur = 0;
    for (int i = 0; i < 16; i++) {
        const int t = c * 16 + i;
        if (i < 15) {
#pragma unroll
            for (int nt = 0; nt < 4; nt++)
#pragma unroll
                for (int r = 0; r < 4; r++) {
                    int s = s0 + (l >> 4) * 4 + r;
                    xwn[nt][r] = rec[((size_t)s * LSEQ + t + 1) * HD + w * 64 + nt * 16 + arow];
                }
        }

        f32x4 acc[4];
#pragma unroll
        for (int nt = 0; nt < 4; nt++) acc[nt] = (f32x4)0.f;

#pragma unroll
        for (int kk = 0; kk < 8; kk++) {
            f16x8 a_r = *reinterpret_cast<const f16x8*>(&hb[cur][arow][(kk + 8) * 32 + ak]);
            f16x8 a_s = *reinterpret_cast<const f16x8*>(&hb[cur][arow][kk * 32 + ak]);
#pragma unroll
            for (int nt = 0; nt < 4; nt++)
                acc[nt] = __builtin_amdgcn_mfma_f32_16x16x32_f16(a_r, breg[kk][nt], acc[nt], 0, 0, 0);
#pragma unroll
            for (int nt = 0; nt < 4; nt++)
                acc[nt] = __builtin_amdgcn_mfma_f32_16x16x32_f16(a_s, sb[kk & 1][nt], acc[nt], 0, 0, 0);
            // reload: kk<6 -> this step's kk+2; kk>=6 -> NEXT step's kk-6 (0/1)
            {
                const int src = (kk < 6) ? (kk + 2) : (kk - 6);
#pragma unroll
                for (int nt = 0; nt < 4; nt++)
                    sb[kk & 1][nt] = *reinterpret_cast<const f16x8*>(
                        bbase + (size_t)(src * 32 + w * 4 + nt) * 512);
            }
        }

        const int nxt = cur ^ 1;
#pragma unroll
        for (int nt = 0; nt < 4; nt++)
#pragma unroll
            for (int r = 0; r < 4; r++) {
                int rr = (l >> 4) * 4 + r;
                int col = w * 64 + nt * 16 + arow;
                float hv = acc[nt][r] + xwv[nt][r];
                hb[nxt][rr][col] = (f16)hv;
                int s = s0 + rr;
                rec[((size_t)s * LSEQ + t) * HD + col] = hv;
            }
        __syncthreads();
#pragma unroll
        for (int nt = 0; nt < 4; nt++)
#pragma unroll
            for (int r = 0; r < 4; r++) xwv[nt][r] = xwn[nt][r];
        cur = nxt;
    }
}

// ---------------------------------------------------------------------------
// phaseB v4: same treatment (resident breg, L(c+1) prefetch, wrapped sb).
// ---------------------------------------------------------------------------
__global__ __launch_bounds__(512, 1) void phaseB(float* __restrict__ rec,
                                                 const f16* __restrict__ T16,
                                                 f16* __restrict__ Hb) {
    __shared__ f16 hb[2][16][520];
    const int tid = threadIdx.x, w = tid >> 6, l = tid & 63;
    const int s0 = blockIdx.x * 16;
    const int arow = l & 15, ak = (l >> 4) * 8;
    const f16* bbase = T16 + (size_t)l * 8;

    f16x8 breg[8][4];
#pragma unroll
    for (int kk = 0; kk < 8; kk++)
#pragma unroll
        for (int nt = 0; nt < 4; nt++)
            breg[kk][nt] = *reinterpret_cast<const f16x8*>(
                bbase + (size_t)((kk + 8) * 32 + w * 4 + nt) * 512);
    f16x8 sb[2][4];
#pragma unroll
    for (int q = 0; q < 2; q++)
#pragma unroll
        for (int nt = 0; nt < 4; nt++)
            sb[q][nt] = *reinterpret_cast<const f16x8*>(
                bbase + (size_t)(q * 32 + w * 4 + nt) * 512);

    // c = 0: H_0 = L_{0,15}
#pragma unroll
    for (int nt = 0; nt < 4; nt++)
#pragma unroll
        for (int r = 0; r < 4; r++) {
            int rr = (l >> 4) * 4 + r;
            int col = w * 64 + nt * 16 + arow;
            int s = s0 + rr;
            float v = rec[((size_t)s * LSEQ + 15) * HD + col];
            hb[0][rr][col] = (f16)v;
            Hb[(size_t)s * HD + col] = (f16)v;
        }
    float Lv[4][4], Lvn[4][4];
#pragma unroll
    for (int nt = 0; nt < 4; nt++)
#pragma unroll
        for (int r = 0; r < 4; r++) {
            int s = s0 + (l >> 4) * 4 + r;
            Lv[nt][r] = rec[((size_t)s * LSEQ + 31) * HD + w * 64 + nt * 16 + arow];
        }
    __syncthreads();

    int cur = 0;
    for (int c = 1; c < 16; c++) {
        const int t = c * 16 + 15;
        if (c < 15) {
#pragma unroll
            for (int nt = 0; nt < 4; nt++)
#pragma unroll
                for (int r = 0; r < 4; r++) {
                    int s = s0 + (l >> 4) * 4 + r;
                    Lvn[nt][r] = rec[((size_t)s * LSEQ + t + 16) * HD + w * 64 + nt * 16 + arow];
                }
        }
        f32x4 acc[4];
#pragma unroll
        for (int nt = 0; nt < 4; nt++) acc[nt] = (f32x4)0.f;

#pragma unroll
        for (int kk = 0; kk < 8; kk++) {
            f16x8 a_r = *reinterpret_cast<const f16x8*>(&hb[cur][arow][(kk + 8) * 32 + ak]);
            f16x8 a_s = *reinterpret_cast<const f16x8*>(&hb[cur][arow][kk * 32 + ak]);
#pragma unroll
            for (int nt = 0; nt < 4; nt++)
                acc[nt] = __builtin_amdgcn_mfma_f32_16x16x32_f16(a_r, breg[kk][nt], acc[nt], 0, 0, 0);
#pragma unroll
            for (int nt = 0; nt < 4; nt++)
                acc[nt] = __builtin_amdgcn_mfma_f32_16x16x32_f16(a_s, sb[kk & 1][nt], acc[nt], 0, 0, 0);
            {
                const int src = (kk < 6) ? (kk + 2) : (kk - 6);
#pragma unroll
                for (int nt = 0; nt < 4; nt++)
                    sb[kk & 1][nt] = *reinterpret_cast<const f16x8*>(
                        bbase + (size_t)(src * 32 + w * 4 + nt) * 512);
            }
        }

        const int nxt = cur ^ 1;
#pragma unroll
        for (int nt = 0; nt < 4; nt++)
#pragma unroll
            for (int r = 0; r < 4; r++) {
                int rr = (l >> 4) * 4 + r;
                int col = w * 64 + nt * 16 + arow;
                float hv = acc[nt][r] + Lv[nt][r];
                hb[nxt][rr][col] = (f16)hv;
                int s = s0 + rr;
                rec[((size_t)s * LSEQ + t) * HD + col] = hv;
                Hb[((size_t)c * NBSEQ + s) * HD + col] = (f16)hv;
            }
        __syncthreads();
#pragma unroll
        for (int nt = 0; nt < 4; nt++)
#pragma unroll
            for (int r = 0; r < 4; r++) Lv[nt][r] = Lvn[nt][r];
        cur = nxt;
    }
}

// ---------------------------------------------------------------------------
// phaseC (+ fused Pb): bx<450: rec[s,16c+i] += Hb[c-1] @ A^(i+1);
// bx>=450: Pb_c = H15 @ A^{16c}, c=1..5 (f16 to Pb buffer).
// ---------------------------------------------------------------------------
__global__ __launch_bounds__(512, 1) void phaseC(float* __restrict__ rec,
                                                 const f16* __restrict__ ws,
                                                 const f16* __restrict__ Hb,
                                                 f16* __restrict__ Pb) {
    __shared__ f16 Al[2][128][40];
    const int tid = threadIdx.x;
    const int w = tid >> 6, l = tid & 63;

    f32x4 acc[8][4];
#pragma unroll
    for (int mt = 0; mt < 8; mt++)
#pragma unroll
        for (int nt = 0; nt < 4; nt++) acc[mt][nt] = (f32x4)0.f;

    if (blockIdx.x < 450) {
        const int p = blockIdx.x >> 1, half = blockIdx.x & 1;
        const int i = p / 15, c = 1 + p % 15;
        const int m0 = half * 128;
        core128(Hb + ((size_t)(c - 1) * NBSEQ + m0) * HD, ws + (size_t)SLOT * (i + 1), Al, acc, tid);
        const int t = c * 16 + i;
#pragma unroll
        for (int mt = 0; mt < 8; mt++)
#pragma unroll
            for (int nt = 0; nt < 4; nt++)
#pragma unroll
                for (int r = 0; r < 4; r++) {
                    int s = m0 + mt * 16 + (l >> 4) * 4 + r;
                    int col = w * 64 + nt * 16 + (l & 15);
                    rec[((size_t)s * LSEQ + t) * HD + col] += acc[mt][nt][r];
                }
    } else {
        const int q = blockIdx.x - 450;           // 0..9
        const int c = 1 + (q >> 1), half = q & 1;
        const int m0 = half * 128;
        // TB slots: c=1 -> T16 (slot16), c=2..5 -> slots 17..20
        core128(Hb + ((size_t)15 * NBSEQ + m0) * HD, ws + (size_t)SLOT * (15 + c), Al, acc, tid);
#pragma unroll
        for (int mt = 0; mt < 8; mt++)
#pragma unroll
            for (int nt = 0; nt < 4; nt++)
#pragma unroll
                for (int r = 0; r < 4; r++) {
                    int s = m0 + mt * 16 + (l >> 4) * 4 + r;
                    int col = w * 64 + nt * 16 + (l & 15);
                    Pb[((size_t)(c - 1) * NBSEQ + s) * HD + col] = (f16)acc[mt][nt][r];
                }
    }
}

// ---------------------------------------------------------------------------
// predLN: outs[s,t-1] = LN(Pb_c @ A^i), t=16c+i. Uses only T1..T16 (L2-hot).
// ---------------------------------------------------------------------------
__global__ __launch_bounds__(512, 1) void predLN(const float* __restrict__ gamma,
                                                 const float* __restrict__ beta,
                                                 const f16* __restrict__ ws,
                                                 const f16* __restrict__ Hb,
                                                 const f16* __restrict__ Pb,
                                                 float* __restrict__ outs) {
    __shared__ f16 Al[2][128][40];
    __shared__ float psum[8][128], psq[8][128], gl[HD], bl[HD];
    const int tid = threadIdx.x;
    const int t = 1 + (blockIdx.x >> 1), half = blockIdx.x & 1;
    const int c = (t - 1) >> 4;                   // 0..5
    const int i = ((t - 1) & 15) + 1;             // 1..16
    const int m0 = half * 128;
    gl[tid] = gamma[tid];
    bl[tid] = beta[tid];

    f32x4 acc[8][4];
#pragma unroll
    for (int mt = 0; mt < 8; mt++)
#pragma unroll
        for (int nt = 0; nt < 4; nt++) acc[mt][nt] = (f32x4)0.f;

    const f16* Asrc = (c == 0) ? (Hb + ((size_t)15 * NBSEQ + m0) * HD)
                               : (Pb + ((size_t)(c - 1) * NBSEQ + m0) * HD);
    core128(Asrc, ws + (size_t)SLOT * i, Al, acc, tid);

    const int w = tid >> 6, l = tid & 63;
#pragma unroll
    for (int mt = 0; mt < 8; mt++)
#pragma unroll
        for (int r = 0; r < 4; r++) {
            int rloc = mt * 16 + (l >> 4) * 4 + r;
            float s1 = 0.f, s2 = 0.f;
#pragma unroll
            for (int nt = 0; nt < 4; nt++) {
                float v = acc[mt][nt][r];
                s1 += v; s2 += v * v;
            }
#pragma unroll
            for (int m = 8; m >= 1; m >>= 1) {
                s1 += __shfl_xor(s1, m);
                s2 += __shfl_xor(s2, m);
            }
            if ((l & 15) == 0) { psum[w][rloc] = s1; psq[w][rloc] = s2; }
        }
    __syncthreads();
#pragma unroll
    for (int mt = 0; mt < 8; mt++)
#pragma unroll
        for (int r = 0; r < 4; r++) {
            int rloc = mt * 16 + (l >> 4) * 4 + r;
            float tot = 0.f, tq = 0.f;
#pragma unroll
            for (int ww = 0; ww < 8; ww++) { tot += psum[ww][rloc]; tq += psq[ww][rloc]; }
            float mean = tot * (1.f / 512.f);
            float var = tq * (1.f / 512.f) - mean * mean;
            float rstd = rsqrtf(var + 1e-5f);
            int s = m0 + rloc;
#pragma unroll
            for (int nt = 0; nt < 4; nt++) {
                int col = w * 64 + nt * 16 + (l & 15);
                outs[((size_t)s * PREDN + (t - 1)) * HD + col] =
                    (acc[mt][nt][r] - mean) * rstd * gl[col] + bl[col];
            }
        }
}

extern "C" void kernel_launch(void* const* d_in, const int* in_sizes, int n_in,
                              void* d_out, int out_size, void* d_ws, size_t ws_size,
                              hipStream_t stream) {
    (void)in_sizes; (void)n_in; (void)out_size; (void)ws_size;
    const float* x     = (const float*)d_in[0];
    const float* Wxh   = (const float*)d_in[1];
    const float* Whh   = (const float*)d_in[2];
    const float* gamma = (const float*)d_in[3];
    const float* beta  = (const float*)d_in[4];
    float* out = (float*)d_out;
    float* outs = out + (size_t)NBSEQ * LSEQ * HD;
    f16* ws = (f16*)d_ws;                         // 19.5 MB used

    f16* R1  = ws + (size_t)SLOT * 21;
    f16* R2  = ws + (size_t)SLOT * 22;
    f16* R4  = ws + (size_t)SLOT * 23;
    f16* R8  = ws + (size_t)SLOT * 24;
    f16* R16 = ws + (size_t)SLOT * 25;
    f16* R32 = ws + (size_t)SLOT * 26;
    f16* R64 = ws + (size_t)SLOT * 27;
    f16* Hb  = ws + (size_t)SLOT * 28;
    f16* Pb  = ws + (size_t)SLOT * 36;
    f16* T16 = ws + (size_t)SLOT * 16;
    f16* T32 = ws + (size_t)SLOT * 17;
    f16* T48 = ws + (size_t)SLOT * 18;
    f16* T64 = ws + (size_t)SLOT * 19;
    f16* T80 = ws + (size_t)SLOT * 20;

    hipLaunchKernelGGL(prep, dim3(192), dim3(512), 0, stream, Wxh, Whh, ws);
    hipLaunchKernelGGL(gemm_xw, dim3(512), dim3(512), 0, stream, x, ws, out);
    hipLaunchKernelGGL(powlevel, dim3(4),  dim3(512), 0, stream, R1, ws, R2,  1);
    hipLaunchKernelGGL(powlevel, dim3(8),  dim3(512), 0, stream, R2, ws, R4,  2);
    hipLaunchKernelGGL(powlevel, dim3(16), dim3(512), 0, stream, R4, ws, R8,  4);
    hipLaunchKernelGGL(powlevel, dim3(32), dim3(512), 0, stream, R8, ws, R16, 8);
    hipLaunchKernelGGL(powB, dim3(4), dim3(512), 0, stream, R16, T16, T32, (const f16*)nullptr, (f16*)nullptr, R32, 0);
    hipLaunchKernelGGL(powB, dim3(8), dim3(512), 0, stream, R32, T16, T48, (const f16*)T32, T64, R64, 1);
    hipLaunchKernelGGL(powB, dim3(4), dim3(512), 0, stream, R64, T16, T80, (const f16*)nullptr, (f16*)nullptr, (f16*)nullptr, -1);
    hipLaunchKernelGGL(phaseA, dim3(256), dim3(512), 0, stream, out, ws + (size_t)SLOT * 1);
    hipLaunchKernelGGL(phaseB, dim3(16),  dim3(512), 0, stream, out, T16, Hb);
    hipLaunchKernelGGL(phaseC, dim3(460), dim3(512), 0, stream, out, ws, Hb, Pb);
    hipLaunchKernelGGL(predLN, dim3(192), dim3(512), 0, stream, gamma, beta, ws, Hb, Pb, outs);
}

// Round 5
// 672.456 us; speedup vs baseline: 1.1272x; 1.1272x over previous
//
#include <hip/hip_runtime.h>

typedef _Float16 f16;
typedef __attribute__((ext_vector_type(8))) _Float16 f16x8;
typedef __attribute__((ext_vector_type(4))) float f32x4;

#define HD 512
#define NBSEQ 256
#define LSEQ 256
#define PREDN 96
#define SLOT 262144   // f16 elements per 512x512 matrix

// ws layout (f16), 39 SLOTs = 19.5 MB:
//   slot 0      : TX (Wxh swizzled)
//   slot 1..16  : T1..T16      (T-form of A^k, A = Whh^T)
//   slot 21..25 : R1,R2,R4,R8,R16 (row-major f16; R16 written but unused)
//   slot 28..35 : Hb [16][256][512] f16
//   slot 36..38 : Pb [5][256][512] f16  (Pb_c = H15 @ A^{16c}, c=1..5)
// T-form: T(kk,nt,lane,j) = M[k][n], k=kk*32+(lane>>4)*8+j, n=nt*16+(lane&15)

// ---------------------------------------------------------------------------
__global__ __launch_bounds__(512) void prep(const float* __restrict__ Wxh,
                                            const float* __restrict__ Whh,
                                            f16* __restrict__ ws) {
    int gid = blockIdx.x * 512 + threadIdx.x;     // grid 192 -> gid < 98304
    if (gid < 65536) {
        int table = gid >> 15;
        int rem = gid & 32767;
        int kk = rem >> 11;
        int nt = (rem >> 6) & 31;
        int l = rem & 63;
        int n = nt * 16 + (l & 15);
        int k = kk * 32 + (l >> 4) * 8;
        const float* W = (table ? Whh : Wxh) + (size_t)n * HD + k;
        f16x8 v;
#pragma unroll
        for (int j = 0; j < 8; j++) v[j] = (f16)W[j];
        *reinterpret_cast<f16x8*>(ws + (size_t)gid * 8) = v;
    } else {
        int idx = gid - 65536;                    // 0..32767
        int m = idx >> 6, kc = (idx & 63) * 8;
        f16* R1 = ws + (size_t)SLOT * 21;
        f16x8 v;
#pragma unroll
        for (int j = 0; j < 8; j++) v[j] = (f16)Whh[(size_t)(kc + j) * HD + m];
        *reinterpret_cast<f16x8*>(R1 + (size_t)m * HD + kc) = v;
    }
}

// ---------------------------------------------------------------------------
// gemm_xw: xW = x @ Wxh^T -> fp32 in-place into rec. (R3-exact, (512,2))
// ---------------------------------------------------------------------------
__global__ __launch_bounds__(512, 2) void gemm_xw(const float* __restrict__ x,
                                                  const f16* __restrict__ bsw,
                                                  float* __restrict__ xw) {
    __shared__ f16 Al[2][128][40];
    __shared__ f16 Bl[2][16384];
    const int tid = threadIdx.x;
    const int w = tid >> 6, l = tid & 63;
    const size_t r0 = (size_t)blockIdx.x * 128;

    f32x4 acc[8][4];
#pragma unroll
    for (int mt = 0; mt < 8; mt++)
#pragma unroll
        for (int nt = 0; nt < 4; nt++) acc[mt][nt] = (f32x4)0.f;

    const int arow_l = l & 15;
    const int akc = (l >> 4) * 8;
    const int srow = tid >> 2, sc8 = (tid & 3) * 8;

    for (int kk = 0; kk < 16; kk++) {
        const int buf = kk & 1;
        {
            const float* src = x + (r0 + srow) * HD + kk * 32 + sc8;
            float4 f0 = *reinterpret_cast<const float4*>(src);
            float4 f1 = *reinterpret_cast<const float4*>(src + 4);
            f16x8 a;
            a[0] = (f16)f0.x; a[1] = (f16)f0.y; a[2] = (f16)f0.z; a[3] = (f16)f0.w;
            a[4] = (f16)f1.x; a[5] = (f16)f1.y; a[6] = (f16)f1.z; a[7] = (f16)f1.w;
            *reinterpret_cast<f16x8*>(&Al[buf][srow][sc8]) = a;
        }
        {
            const f16* bsrc = bsw + (size_t)kk * 16384 + tid * 8;
#pragma unroll
            for (int i = 0; i < 4; i++)
                *reinterpret_cast<f16x8*>(&Bl[buf][i * 4096 + tid * 8]) =
                    *reinterpret_cast<const f16x8*>(bsrc + i * 4096);
        }
        __syncthreads();

        f16x8 af[8];
#pragma unroll
        for (int mt = 0; mt < 8; mt++)
            af[mt] = *reinterpret_cast<const f16x8*>(&Al[buf][mt * 16 + arow_l][akc]);
#pragma unroll
        for (int nt = 0; nt < 4; nt++) {
            f16x8 bf = *reinterpret_cast<const f16x8*>(&Bl[buf][((w * 4 + nt) * 64 + l) * 8]);
#pragma unroll
            for (int mt = 0; mt < 8; mt++)
                acc[mt][nt] = __builtin_amdgcn_mfma_f32_16x16x32_f16(af[mt], bf, acc[mt][nt], 0, 0, 0);
        }
    }
#pragma unroll
    for (int mt = 0; mt < 8; mt++)
#pragma unroll
        for (int nt = 0; nt < 4; nt++)
#pragma unroll
            for (int r = 0; r < 4; r++) {
                size_t row = r0 + mt * 16 + (l >> 4) * 4 + r;
                int col = w * 64 + nt * 16 + arow_l;
                xw[row * HD + col] = acc[mt][nt][r];
            }
}

// ---------------------------------------------------------------------------
// core128: C[128,512] = A[128,512](f16 row-major) @ Y(T-form), K=512.
// ---------------------------------------------------------------------------
__device__ __forceinline__ void core128(const f16* __restrict__ Asrc,
                                        const f16* __restrict__ Y,
                                        f16 (*Al)[128][40],
                                        f32x4 (*acc)[4], int tid) {
    const int w = tid >> 6, l = tid & 63;
    const int srow = tid >> 2, sc8 = (tid & 3) * 8;
    const int arow = l & 15, ak = (l >> 4) * 8;
    for (int kk = 0; kk < 16; kk++) {
        const int buf = kk & 1;
        *reinterpret_cast<f16x8*>(&Al[buf][srow][sc8]) =
            *reinterpret_cast<const f16x8*>(Asrc + (size_t)srow * HD + kk * 32 + sc8);
        __syncthreads();
        f16x8 af[8];
#pragma unroll
        for (int mt = 0; mt < 8; mt++)
            af[mt] = *reinterpret_cast<const f16x8*>(&Al[buf][mt * 16 + arow][ak]);
#pragma unroll
        for (int nt = 0; nt < 4; nt++) {
            f16x8 b = *reinterpret_cast<const f16x8*>(Y + (size_t)(kk * 32 + w * 4 + nt) * 512 + l * 8);
#pragma unroll
            for (int mt = 0; mt < 8; mt++)
                acc[mt][nt] = __builtin_amdgcn_mfma_f32_16x16x32_f16(af[mt], b, acc[mt][nt], 0, 0, 0);
        }
    }
}

// T-form scatter index for value M[m][n]
__device__ __forceinline__ size_t tform_ix(int m, int n) {
    return (((size_t)(m >> 5) * 32 + (n >> 4)) * 64 +
            (((m >> 3) & 3) * 16 + (n & 15))) * 8 + (m & 7);
}

// ---------------------------------------------------------------------------
// powlevel: doubling level h (verified R2/R3). out T[h+1+j0] = R @ T[1+j0].
// ---------------------------------------------------------------------------
__global__ __launch_bounds__(512, 2) void powlevel(const f16* __restrict__ RX,
                                                   f16* __restrict__ ws,
                                                   f16* __restrict__ Rsq,
                                                   int h) {
    __shared__ f16 Al[2][128][40];
    const int tid = threadIdx.x;
    const int j0 = blockIdx.x >> 2, mtile = blockIdx.x & 3;
    const int m0 = mtile * 128;
    const f16* Y = ws + (size_t)SLOT * (1 + j0);
    f16* Tout = ws + (size_t)SLOT * (h + 1 + j0);

    f32x4 acc[8][4];
#pragma unroll
    for (int mt = 0; mt < 8; mt++)
#pragma unroll
        for (int nt = 0; nt < 4; nt++) acc[mt][nt] = (f32x4)0.f;

    core128(RX + (size_t)m0 * HD, Y, Al, acc, tid);

    const int w = tid >> 6, l = tid & 63;
    const bool doR = (1 + j0) == h;
#pragma unroll
    for (int mt = 0; mt < 8; mt++)
#pragma unroll
        for (int nt = 0; nt < 4; nt++)
#pragma unroll
            for (int r = 0; r < 4; r++) {
                int m = m0 + mt * 16 + (l >> 4) * 4 + r;
                int n = w * 64 + nt * 16 + (l & 15);
                f16 v = (f16)acc[mt][nt][r];
                Tout[tform_ix(m, n)] = v;
                if (doR) Rsq[(size_t)m * HD + n] = v;
            }
}

// ---------------------------------------------------------------------------
// phaseA v5: breg FORCED resident (waves_per_eu(2,2) + asm pin), xW(t+1)
// prefetched, streamed-B pipeline wraps across steps. 256 WGs, M=16.
// ---------------------------------------------------------------------------
__global__ __launch_bounds__(512)
__attribute__((amdgpu_waves_per_eu(2, 2)))
void phaseA(float* __restrict__ rec, const f16* __restrict__ T1) {
    __shared__ f16 hb[2][16][520];
    const int tid = threadIdx.x, w = tid >> 6, l = tid & 63;
    const int c = blockIdx.x >> 4, sg = blockIdx.x & 15;
    const int s0 = sg * 16;
    {
        f16* hp = &hb[0][0][0];
        for (int i = tid; i < 16 * 520; i += 512) hp[i] = (f16)0.f;
    }
    const int arow = l & 15, ak = (l >> 4) * 8;
    const f16* bbase = T1 + (size_t)l * 8;

    // resident half: kk = 8..15 (128 VGPR). The asm pin makes each value an
    // opaque def -> the compiler cannot re-materialize the load inside the
    // loop (the R3/R4 failure mode); waves_per_eu(2,2) grants the 256 budget.
    f16x8 breg[8][4];
#pragma unroll
    for (int kk = 0; kk < 8; kk++)
#pragma unroll
        for (int nt = 0; nt < 4; nt++) {
            breg[kk][nt] = *reinterpret_cast<const f16x8*>(
                bbase + (size_t)((kk + 8) * 32 + w * 4 + nt) * 512);
            asm volatile("" : "+v"(breg[kk][nt]));
        }

    // streamed-half pipeline registers; invariant: at step entry sb[q] = kk q
    f16x8 sb[2][4];
#pragma unroll
    for (int q = 0; q < 2; q++)
#pragma unroll
        for (int nt = 0; nt < 4; nt++)
            sb[q][nt] = *reinterpret_cast<const f16x8*>(
                bbase + (size_t)(q * 32 + w * 4 + nt) * 512);

    // xW prefetch for t0
    float xwv[4][4], xwn[4][4];
#pragma unroll
    for (int nt = 0; nt < 4; nt++)
#pragma unroll
        for (int r = 0; r < 4; r++) {
            int s = s0 + (l >> 4) * 4 + r;
            xwv[nt][r] = rec[((size_t)s * LSEQ + c * 16) * HD + w * 64 + nt * 16 + arow];
        }
    __syncthreads();

    int cur = 0;
    for (int i = 0; i < 16; i++) {
        const int t = c * 16 + i;
        if (i < 15) {
#pragma unroll
            for (int nt = 0; nt < 4; nt++)
#pragma unroll
                for (int r = 0; r < 4; r++) {
                    int s = s0 + (l >> 4) * 4 + r;
                    xwn[nt][r] = rec[((size_t)s * LSEQ + t + 1) * HD + w * 64 + nt * 16 + arow];
                }
        }

        f32x4 acc[4];
#pragma unroll
        for (int nt = 0; nt < 4; nt++) acc[nt] = (f32x4)0.f;

#pragma unroll
        for (int kk = 0; kk < 8; kk++) {
            f16x8 a_r = *reinterpret_cast<const f16x8*>(&hb[cur][arow][(kk + 8) * 32 + ak]);
            f16x8 a_s = *reinterpret_cast<const f16x8*>(&hb[cur][arow][kk * 32 + ak]);
#pragma unroll
            for (int nt = 0; nt < 4; nt++)
                acc[nt] = __builtin_amdgcn_mfma_f32_16x16x32_f16(a_r, breg[kk][nt], acc[nt], 0, 0, 0);
#pragma unroll
            for (int nt = 0; nt < 4; nt++)
                acc[nt] = __builtin_amdgcn_mfma_f32_16x16x32_f16(a_s, sb[kk & 1][nt], acc[nt], 0, 0, 0);
            // reload: kk<6 -> this step's kk+2; kk>=6 -> NEXT step's kk-6 (0/1)
            {
                const int src = (kk < 6) ? (kk + 2) : (kk - 6);
#pragma unroll
                for (int nt = 0; nt < 4; nt++)
                    sb[kk & 1][nt] = *reinterpret_cast<const f16x8*>(
                        bbase + (size_t)(src * 32 + w * 4 + nt) * 512);
            }
        }

        const int nxt = cur ^ 1;
#pragma unroll
        for (int nt = 0; nt < 4; nt++)
#pragma unroll
            for (int r = 0; r < 4; r++) {
                int rr = (l >> 4) * 4 + r;
                int col = w * 64 + nt * 16 + arow;
                float hv = acc[nt][r] + xwv[nt][r];
                hb[nxt][rr][col] = (f16)hv;
                int s = s0 + rr;
                rec[((size_t)s * LSEQ + t) * HD + col] = hv;
            }
        __syncthreads();
#pragma unroll
        for (int nt = 0; nt < 4; nt++)
#pragma unroll
            for (int r = 0; r < 4; r++) xwv[nt][r] = xwn[nt][r];
        cur = nxt;
    }
}

// ---------------------------------------------------------------------------
// phaseB v5: resident breg (forced), L(c+1) prefetch, and a 5-step tail that
// produces Pb_c = H15 @ A^{16c} (c=1..5) -- replaces the powB launch chain.
// 16 WGs, M=16.
// ---------------------------------------------------------------------------
__global__ __launch_bounds__(512)
__attribute__((amdgpu_waves_per_eu(2, 2)))
void phaseB(float* __restrict__ rec, const f16* __restrict__ T16,
            f16* __restrict__ Hb, f16* __restrict__ Pb) {
    __shared__ f16 hb[2][16][520];
    const int tid = threadIdx.x, w = tid >> 6, l = tid & 63;
    const int s0 = blockIdx.x * 16;
    const int arow = l & 15, ak = (l >> 4) * 8;
    const f16* bbase = T16 + (size_t)l * 8;

    f16x8 breg[8][4];
#pragma unroll
    for (int kk = 0; kk < 8; kk++)
#pragma unroll
        for (int nt = 0; nt < 4; nt++) {
            breg[kk][nt] = *reinterpret_cast<const f16x8*>(
                bbase + (size_t)((kk + 8) * 32 + w * 4 + nt) * 512);
            asm volatile("" : "+v"(breg[kk][nt]));
        }
    f16x8 sb[2][4];
#pragma unroll
    for (int q = 0; q < 2; q++)
#pragma unroll
        for (int nt = 0; nt < 4; nt++)
            sb[q][nt] = *reinterpret_cast<const f16x8*>(
                bbase + (size_t)(q * 32 + w * 4 + nt) * 512);

    // c = 0: H_0 = L_{0,15}
#pragma unroll
    for (int nt = 0; nt < 4; nt++)
#pragma unroll
        for (int r = 0; r < 4; r++) {
            int rr = (l >> 4) * 4 + r;
            int col = w * 64 + nt * 16 + arow;
            int s = s0 + rr;
            float v = rec[((size_t)s * LSEQ + 15) * HD + col];
            hb[0][rr][col] = (f16)v;
            Hb[(size_t)s * HD + col] = (f16)v;
        }
    float Lv[4][4], Lvn[4][4];
#pragma unroll
    for (int nt = 0; nt < 4; nt++)
#pragma unroll
        for (int r = 0; r < 4; r++) {
            int s = s0 + (l >> 4) * 4 + r;
            Lv[nt][r] = rec[((size_t)s * LSEQ + 31) * HD + w * 64 + nt * 16 + arow];
        }
    __syncthreads();

    int cur = 0;
    for (int c = 1; c < 21; c++) {                 // 1..15 carries, 16..20 Pb tail
        const bool carry = (c < 16);
        const int t = c * 16 + 15;
        if (c < 15) {
#pragma unroll
            for (int nt = 0; nt < 4; nt++)
#pragma unroll
                for (int r = 0; r < 4; r++) {
                    int s = s0 + (l >> 4) * 4 + r;
                    Lvn[nt][r] = rec[((size_t)s * LSEQ + t + 16) * HD + w * 64 + nt * 16 + arow];
                }
        }
        f32x4 acc[4];
#pragma unroll
        for (int nt = 0; nt < 4; nt++) acc[nt] = (f32x4)0.f;

#pragma unroll
        for (int kk = 0; kk < 8; kk++) {
            f16x8 a_r = *reinterpret_cast<const f16x8*>(&hb[cur][arow][(kk + 8) * 32 + ak]);
            f16x8 a_s = *reinterpret_cast<const f16x8*>(&hb[cur][arow][kk * 32 + ak]);
#pragma unroll
            for (int nt = 0; nt < 4; nt++)
                acc[nt] = __builtin_amdgcn_mfma_f32_16x16x32_f16(a_r, breg[kk][nt], acc[nt], 0, 0, 0);
#pragma unroll
            for (int nt = 0; nt < 4; nt++)
                acc[nt] = __builtin_amdgcn_mfma_f32_16x16x32_f16(a_s, sb[kk & 1][nt], acc[nt], 0, 0, 0);
            {
                const int src = (kk < 6) ? (kk + 2) : (kk - 6);
#pragma unroll
                for (int nt = 0; nt < 4; nt++)
                    sb[kk & 1][nt] = *reinterpret_cast<const f16x8*>(
                        bbase + (size_t)(src * 32 + w * 4 + nt) * 512);
            }
        }

        const int nxt = cur ^ 1;
        if (carry) {
#pragma unroll
            for (int nt = 0; nt < 4; nt++)
#pragma unroll
                for (int r = 0; r < 4; r++) {
                    int rr = (l >> 4) * 4 + r;
                    int col = w * 64 + nt * 16 + arow;
                    float hv = acc[nt][r] + Lv[nt][r];
                    hb[nxt][rr][col] = (f16)hv;
                    int s = s0 + rr;
                    rec[((size_t)s * LSEQ + t) * HD + col] = hv;
                    Hb[((size_t)c * NBSEQ + s) * HD + col] = (f16)hv;
                }
        } else {
            const int pc = c - 16;                 // 0..4 -> Pb_{pc+1}
#pragma unroll
            for (int nt = 0; nt < 4; nt++)
#pragma unroll
                for (int r = 0; r < 4; r++) {
                    int rr = (l >> 4) * 4 + r;
                    int col = w * 64 + nt * 16 + arow;
                    float hv = acc[nt][r];         // pure matrix power step
                    hb[nxt][rr][col] = (f16)hv;
                    int s = s0 + rr;
                    Pb[((size_t)pc * NBSEQ + s) * HD + col] = (f16)hv;
                }
        }
        __syncthreads();
#pragma unroll
        for (int nt = 0; nt < 4; nt++)
#pragma unroll
            for (int r = 0; r < 4; r++) Lv[nt][r] = Lvn[nt][r];
        cur = nxt;
    }
}

// ---------------------------------------------------------------------------
// phaseC: fill-in (R3-exact, (512,2)). rec[s,16c+i] += Hb[c-1] @ A^(i+1).
// ---------------------------------------------------------------------------
__global__ __launch_bounds__(512, 2) void phaseC(float* __restrict__ rec,
                                                 const f16* __restrict__ ws,
                                                 const f16* __restrict__ Hb) {
    __shared__ f16 Al[2][128][40];
    const int tid = threadIdx.x;
    const int p = blockIdx.x >> 1, half = blockIdx.x & 1;
    const int i = p / 15, c = 1 + p % 15;
    const int m0 = half * 128;

    f32x4 acc[8][4];
#pragma unroll
    for (int mt = 0; mt < 8; mt++)
#pragma unroll
        for (int nt = 0; nt < 4; nt++) acc[mt][nt] = (f32x4)0.f;

    core128(Hb + ((size_t)(c - 1) * NBSEQ + m0) * HD, ws + (size_t)SLOT * (i + 1), Al, acc, tid);

    const int w = tid >> 6, l = tid & 63;
    const int t = c * 16 + i;
#pragma unroll
    for (int mt = 0; mt < 8; mt++)
#pragma unroll
        for (int nt = 0; nt < 4; nt++)
#pragma unroll
            for (int r = 0; r < 4; r++) {
                int s = m0 + mt * 16 + (l >> 4) * 4 + r;
                int col = w * 64 + nt * 16 + (l & 15);
                rec[((size_t)s * LSEQ + t) * HD + col] += acc[mt][nt][r];
            }
}

// ---------------------------------------------------------------------------
// predLN: outs[s,t-1] = LN(Pb_c @ A^i), t=16c+i. Uses only T1..T16 (L2-hot).
// ---------------------------------------------------------------------------
__global__ __launch_bounds__(512, 2) void predLN(const float* __restrict__ gamma,
                                                 const float* __restrict__ beta,
                                                 const f16* __restrict__ ws,
                                                 const f16* __restrict__ Hb,
                                                 const f16* __restrict__ Pb,
                                                 float* __restrict__ outs) {
    __shared__ f16 Al[2][128][40];
    __shared__ float psum[8][128], psq[8][128], gl[HD], bl[HD];
    const int tid = threadIdx.x;
    const int t = 1 + (blockIdx.x >> 1), half = blockIdx.x & 1;
    const int c = (t - 1) >> 4;                   // 0..5
    const int i = ((t - 1) & 15) + 1;             // 1..16
    const int m0 = half * 128;
    gl[tid] = gamma[tid];
    bl[tid] = beta[tid];

    f32x4 acc[8][4];
#pragma unroll
    for (int mt = 0; mt < 8; mt++)
#pragma unroll
        for (int nt = 0; nt < 4; nt++) acc[mt][nt] = (f32x4)0.f;

    const f16* Asrc = (c == 0) ? (Hb + ((size_t)15 * NBSEQ + m0) * HD)
                               : (Pb + ((size_t)(c - 1) * NBSEQ + m0) * HD);
    core128(Asrc, ws + (size_t)SLOT * i, Al, acc, tid);

    const int w = tid >> 6, l = tid & 63;
#pragma unroll
    for (int mt = 0; mt < 8; mt++)
#pragma unroll
        for (int r = 0; r < 4; r++) {
            int rloc = mt * 16 + (l >> 4) * 4 + r;
            float s1 = 0.f, s2 = 0.f;
#pragma unroll
            for (int nt = 0; nt < 4; nt++) {
                float v = acc[mt][nt][r];
                s1 += v; s2 += v * v;
            }
#pragma unroll
            for (int m = 8; m >= 1; m >>= 1) {
                s1 += __shfl_xor(s1, m);
                s2 += __shfl_xor(s2, m);
            }
            if ((l & 15) == 0) { psum[w][rloc] = s1; psq[w][rloc] = s2; }
        }
    __syncthreads();
#pragma unroll
    for (int mt = 0; mt < 8; mt++)
#pragma unroll
        for (int r = 0; r < 4; r++) {
            int rloc = mt * 16 + (l >> 4) * 4 + r;
            float tot = 0.f, tq = 0.f;
#pragma unroll
            for (int ww = 0; ww < 8; ww++) { tot += psum[ww][rloc]; tq += psq[ww][rloc]; }
            float mean = tot * (1.f / 512.f);
            float var = tq * (1.f / 512.f) - mean * mean;
            float rstd = rsqrtf(var + 1e-5f);
            int s = m0 + rloc;
#pragma unroll
            for (int nt = 0; nt < 4; nt++) {
                int col = w * 64 + nt * 16 + (l & 15);
                outs[((size_t)s * PREDN + (t - 1)) * HD + col] =
                    (acc[mt][nt][r] - mean) * rstd * gl[col] + bl[col];
            }
        }
}

extern "C" void kernel_launch(void* const* d_in, const int* in_sizes, int n_in,
                              void* d_out, int out_size, void* d_ws, size_t ws_size,
                              hipStream_t stream) {
    (void)in_sizes; (void)n_in; (void)out_size; (void)ws_size;
    const float* x     = (const float*)d_in[0];
    const float* Wxh   = (const float*)d_in[1];
    const float* Whh   = (const float*)d_in[2];
    const float* gamma = (const float*)d_in[3];
    const float* beta  = (const float*)d_in[4];
    float* out = (float*)d_out;
    float* outs = out + (size_t)NBSEQ * LSEQ * HD;
    f16* ws = (f16*)d_ws;                         // 19.5 MB used

    f16* R1  = ws + (size_t)SLOT * 21;
    f16* R2  = ws + (size_t)SLOT * 22;
    f16* R4  = ws + (size_t)SLOT * 23;
    f16* R8  = ws + (size_t)SLOT * 24;
    f16* R16 = ws + (size_t)SLOT * 25;
    f16* Hb  = ws + (size_t)SLOT * 28;
    f16* Pb  = ws + (size_t)SLOT * 36;
    f16* T16 = ws + (size_t)SLOT * 16;

    hipLaunchKernelGGL(prep, dim3(192), dim3(512), 0, stream, Wxh, Whh, ws);
    hipLaunchKernelGGL(gemm_xw, dim3(512), dim3(512), 0, stream, x, ws, out);
    hipLaunchKernelGGL(powlevel, dim3(4),  dim3(512), 0, stream, R1, ws, R2,  1);
    hipLaunchKernelGGL(powlevel, dim3(8),  dim3(512), 0, stream, R2, ws, R4,  2);
    hipLaunchKernelGGL(powlevel, dim3(16), dim3(512), 0, stream, R4, ws, R8,  4);
    hipLaunchKernelGGL(powlevel, dim3(32), dim3(512), 0, stream, R8, ws, R16, 8);
    hipLaunchKernelGGL(phaseA, dim3(256), dim3(512), 0, stream, out, ws + (size_t)SLOT * 1);
    hipLaunchKernelGGL(phaseB, dim3(16),  dim3(512), 0, stream, out, T16, Hb, Pb);
    hipLaunchKernelGGL(phaseC, dim3(450), dim3(512), 0, stream, out, ws, Hb);
    hipLaunchKernelGGL(predLN, dim3(192), dim3(512), 0, stream, gamma, beta, ws, Hb, Pb, outs);
}